// Round 2
// baseline (317.112 us; speedup 1.0000x reference)
//
#include <hip/hip_runtime.h>
#include <math.h>

#define TOPK 8
#define KJ 17
#define BB 512
#define NROWS (BB * KJ)   // 8704
#define DF 3072           // floats per row; 768 float4; 3 float4/thread @ 256 thr

// One block per (b,k) row: squared-diff row sum * weight -> loss[row].
// Last block to finish additionally computes the top-8 mean reduction.
__global__ __launch_bounds__(256) void fused_ohkm_kernel(
    const float* __restrict__ out,
    const float* __restrict__ tgt,
    const float* __restrict__ w,
    float* __restrict__ loss,
    int* __restrict__ counter,
    float* __restrict__ result)
{
    const int row = blockIdx.x;
    const int tid = threadIdx.x;
    const size_t base = (size_t)row * DF;
    const float4* __restrict__ o4 = (const float4*)(out + base);
    const float4* __restrict__ t4 = (const float4*)(tgt + base);

    // issue all 6 loads before any math (MLP)
    float4 a0 = o4[tid];
    float4 a1 = o4[tid + 256];
    float4 a2 = o4[tid + 512];
    float4 b0 = t4[tid];
    float4 b1 = t4[tid + 256];
    float4 b2 = t4[tid + 512];

    float acc;
    {
        float dx = a0.x - b0.x, dy = a0.y - b0.y, dz = a0.z - b0.z, dw = a0.w - b0.w;
        acc = dx * dx + dy * dy + dz * dz + dw * dw;
        dx = a1.x - b1.x; dy = a1.y - b1.y; dz = a1.z - b1.z; dw = a1.w - b1.w;
        acc += dx * dx + dy * dy + dz * dz + dw * dw;
        dx = a2.x - b2.x; dy = a2.y - b2.y; dz = a2.z - b2.z; dw = a2.w - b2.w;
        acc += dx * dx + dy * dy + dz * dz + dw * dw;
    }

    #pragma unroll
    for (int off = 32; off > 0; off >>= 1)
        acc += __shfl_down(acc, off, 64);

    __shared__ float s[4];
    __shared__ bool is_last;
    const int lane = tid & 63;
    const int wid = tid >> 6;
    if (lane == 0) s[wid] = acc;
    __syncthreads();
    if (tid == 0) {
        float tot = s[0] + s[1] + s[2] + s[3];
        loss[row] = tot * w[row];
        __threadfence();  // make loss[row] visible device-wide before count
        int old = atomicAdd(counter, 1);
        is_last = (old == NROWS - 1);
        if (is_last) __threadfence();
    }
    __syncthreads();
    if (!is_last) return;

    // ---- finish phase: only the last block runs this ----
    // thread t handles samples b = t and b = t + 256
    float per2 = 0.0f;
    #pragma unroll
    for (int half = 0; half < 2; ++half) {
        const int b = tid + half * 256;
        float v[KJ];
        #pragma unroll
        for (int k = 0; k < KJ; ++k)
            v[k] = __hip_atomic_load(&loss[b * KJ + k],
                                     __ATOMIC_RELAXED, __HIP_MEMORY_SCOPE_AGENT);
        float sum8 = 0.0f;
        #pragma unroll
        for (int it = 0; it < TOPK; ++it) {
            float m = v[0];
            int mi = 0;
            #pragma unroll
            for (int k = 1; k < KJ; ++k)
                if (v[k] > m) { m = v[k]; mi = k; }
            sum8 += m;
            #pragma unroll
            for (int k = 0; k < KJ; ++k)
                v[k] = (k == mi) ? -INFINITY : v[k];
        }
        per2 += sum8 * (1.0f / (float)TOPK);
    }

    #pragma unroll
    for (int off = 32; off > 0; off >>= 1)
        per2 += __shfl_down(per2, off, 64);

    __shared__ float s2[4];
    if (lane == 0) s2[wid] = per2;
    __syncthreads();
    if (tid == 0) {
        float tot = s2[0] + s2[1] + s2[2] + s2[3];
        result[0] = tot / (float)BB;
    }
}

extern "C" void kernel_launch(void* const* d_in, const int* in_sizes, int n_in,
                              void* d_out, int out_size, void* d_ws, size_t ws_size,
                              hipStream_t stream) {
    const float* out_p = (const float*)d_in[0];
    const float* tgt_p = (const float*)d_in[1];
    const float* w_p   = (const float*)d_in[2];
    float* res = (float*)d_out;

    // d_ws layout: [0..255] counter (only first 4 bytes used), then loss[NROWS]
    int*   counter = (int*)d_ws;
    float* loss_ws = (float*)((char*)d_ws + 256);

    hipMemsetAsync(counter, 0, sizeof(int), stream);
    fused_ohkm_kernel<<<NROWS, 256, 0, stream>>>(out_p, tgt_p, w_p,
                                                 loss_ws, counter, res);
}

// Round 3
// 124.138 us; speedup vs baseline: 2.5545x; 2.5545x over previous
//
#include <hip/hip_runtime.h>
#include <math.h>

#define TOPK 8
#define KJ 17
#define BB 512
#define NROWS (BB * KJ)   // 8704
#define DF 3072           // floats per row; 768 float4; 3 float4/thread @ 256 thr

// One block per (b,k) row: squared-diff row sum * weight -> loss[row].
// Cheap cross-XCD publish: relaxed agent atomic store (sc0 sc1 write-through)
// + s_waitcnt vmcnt(0) + relaxed atomic counter. NO agent-scope fence
// (fence => buffer_wbl2 per block = 450us regression, R2 post-mortem).
__global__ __launch_bounds__(256) void fused_ohkm_kernel(
    const float* __restrict__ out,
    const float* __restrict__ tgt,
    const float* __restrict__ w,
    float* __restrict__ loss,
    int* __restrict__ counter,
    float* __restrict__ result)
{
    const int row = blockIdx.x;
    const int tid = threadIdx.x;
    const size_t base = (size_t)row * DF;
    const float4* __restrict__ o4 = (const float4*)(out + base);
    const float4* __restrict__ t4 = (const float4*)(tgt + base);

    // issue all 6 loads before any math (MLP)
    float4 a0 = o4[tid];
    float4 a1 = o4[tid + 256];
    float4 a2 = o4[tid + 512];
    float4 b0 = t4[tid];
    float4 b1 = t4[tid + 256];
    float4 b2 = t4[tid + 512];

    float acc;
    {
        float dx = a0.x - b0.x, dy = a0.y - b0.y, dz = a0.z - b0.z, dw = a0.w - b0.w;
        acc = dx * dx + dy * dy + dz * dz + dw * dw;
        dx = a1.x - b1.x; dy = a1.y - b1.y; dz = a1.z - b1.z; dw = a1.w - b1.w;
        acc += dx * dx + dy * dy + dz * dz + dw * dw;
        dx = a2.x - b2.x; dy = a2.y - b2.y; dz = a2.z - b2.z; dw = a2.w - b2.w;
        acc += dx * dx + dy * dy + dz * dz + dw * dw;
    }

    #pragma unroll
    for (int off = 32; off > 0; off >>= 1)
        acc += __shfl_down(acc, off, 64);

    __shared__ float s[4];
    __shared__ bool is_last;
    const int lane = tid & 63;
    const int wid = tid >> 6;
    if (lane == 0) s[wid] = acc;
    __syncthreads();
    if (tid == 0) {
        float tot = (s[0] + s[1] + s[2] + s[3]) * w[row];
        // write-through publish to the fabric coherence point (no L2 flush)
        __hip_atomic_store(&loss[row], tot, __ATOMIC_RELAXED,
                           __HIP_MEMORY_SCOPE_AGENT);
        // store must complete at the coherent point before the count ticks
        asm volatile("s_waitcnt vmcnt(0)" ::: "memory");
        int old = __hip_atomic_fetch_add(counter, 1, __ATOMIC_RELAXED,
                                         __HIP_MEMORY_SCOPE_AGENT);
        is_last = (old == NROWS - 1);
    }
    __syncthreads();
    if (!is_last) return;

    // ---- finish phase: only the last block runs this ----
    // thread t handles samples b = t and b = t + 256
    float per2 = 0.0f;
    #pragma unroll
    for (int half = 0; half < 2; ++half) {
        const int b = tid + half * 256;
        float v[KJ];
        #pragma unroll
        for (int k = 0; k < KJ; ++k)
            v[k] = __hip_atomic_load(&loss[b * KJ + k],
                                     __ATOMIC_RELAXED, __HIP_MEMORY_SCOPE_AGENT);
        float sum8 = 0.0f;
        #pragma unroll
        for (int it = 0; it < TOPK; ++it) {
            float m = v[0];
            int mi = 0;
            #pragma unroll
            for (int k = 1; k < KJ; ++k)
                if (v[k] > m) { m = v[k]; mi = k; }
            sum8 += m;
            #pragma unroll
            for (int k = 0; k < KJ; ++k)
                v[k] = (k == mi) ? -INFINITY : v[k];
        }
        per2 += sum8 * (1.0f / (float)TOPK);
    }

    #pragma unroll
    for (int off = 32; off > 0; off >>= 1)
        per2 += __shfl_down(per2, off, 64);

    __shared__ float s2[4];
    if (lane == 0) s2[wid] = per2;
    __syncthreads();
    if (tid == 0) {
        float tot = s2[0] + s2[1] + s2[2] + s2[3];
        result[0] = tot / (float)BB;
    }
}

extern "C" void kernel_launch(void* const* d_in, const int* in_sizes, int n_in,
                              void* d_out, int out_size, void* d_ws, size_t ws_size,
                              hipStream_t stream) {
    const float* out_p = (const float*)d_in[0];
    const float* tgt_p = (const float*)d_in[1];
    const float* w_p   = (const float*)d_in[2];
    float* res = (float*)d_out;

    // d_ws layout: [0..255] counter (only first 4 bytes used), then loss[NROWS]
    int*   counter = (int*)d_ws;
    float* loss_ws = (float*)((char*)d_ws + 256);

    hipMemsetAsync(counter, 0, sizeof(int), stream);
    fused_ohkm_kernel<<<NROWS, 256, 0, stream>>>(out_p, tgt_p, w_p,
                                                 loss_ws, counter, res);
}

// Round 4
// 51.928 us; speedup vs baseline: 6.1067x; 2.3906x over previous
//
#include <hip/hip_runtime.h>
#include <math.h>

#define TOPK 8
#define KJ 17
#define BB 512
#define DF 3072           // floats per row = 768 float4
#define TPB 768           // 12 waves; one float4 per thread per row

// One block per sample b. Computes all 17 weighted row losses in-block,
// top-8 mean, and atomically accumulates the global mean contribution.
// No cross-block sync of any kind (R2/R3 post-mortem: fences/counters
// at 8704-block scale cost 80-450us).
__global__ __launch_bounds__(TPB) void ohkm_per_sample_kernel(
    const float* __restrict__ out,
    const float* __restrict__ tgt,
    const float* __restrict__ w,
    float* __restrict__ result)
{
    const int b = blockIdx.x;
    const int tid = threadIdx.x;
    const int lane = tid & 63;
    const int wid = tid >> 6;           // 0..11

    const float4* __restrict__ o4 = (const float4*)(out + (size_t)b * KJ * DF);
    const float4* __restrict__ t4 = (const float4*)(tgt + (size_t)b * KJ * DF);

    // per-thread squared-diff partial for each of the 17 rows
    float acc[KJ];
    #pragma unroll
    for (int k = 0; k < KJ; ++k) {
        float4 a = o4[k * TPB + tid];
        float4 c = t4[k * TPB + tid];
        float dx = a.x - c.x;
        float dy = a.y - c.y;
        float dz = a.z - c.z;
        float dw = a.w - c.w;
        acc[k] = dx * dx + dy * dy + dz * dz + dw * dw;
    }

    // wave-64 reduce each row partial; wave leaders write to LDS
    __shared__ float part[12][KJ + 1];   // +1 pad (trivial size anyway)
    #pragma unroll
    for (int k = 0; k < KJ; ++k) {
        float v = acc[k];
        v += __shfl_down(v, 32, 64);
        v += __shfl_down(v, 16, 64);
        v += __shfl_down(v, 8, 64);
        v += __shfl_down(v, 4, 64);
        v += __shfl_down(v, 2, 64);
        v += __shfl_down(v, 1, 64);
        if (lane == 0) part[wid][k] = v;
    }
    __syncthreads();

    // threads 0..16: sum the 12 wave partials for row k, apply weight
    __shared__ float rowloss[KJ];
    if (tid < KJ) {
        float v = 0.0f;
        #pragma unroll
        for (int ww = 0; ww < 12; ++ww)
            v += part[ww][tid];
        rowloss[tid] = v * w[b * KJ + tid];
    }
    __syncthreads();

    // thread 0: top-8 of 17, contribute to global mean
    if (tid == 0) {
        float v[KJ];
        #pragma unroll
        for (int k = 0; k < KJ; ++k)
            v[k] = rowloss[k];
        float sum8 = 0.0f;
        #pragma unroll
        for (int it = 0; it < TOPK; ++it) {
            float m = v[0];
            int mi = 0;
            #pragma unroll
            for (int k = 1; k < KJ; ++k)
                if (v[k] > m) { m = v[k]; mi = k; }
            sum8 += m;
            #pragma unroll
            for (int k = 0; k < KJ; ++k)
                v[k] = (k == mi) ? -INFINITY : v[k];
        }
        atomicAdd(result, sum8 * (1.0f / (float)(TOPK * BB)));
    }
}

extern "C" void kernel_launch(void* const* d_in, const int* in_sizes, int n_in,
                              void* d_out, int out_size, void* d_ws, size_t ws_size,
                              hipStream_t stream) {
    const float* out_p = (const float*)d_in[0];
    const float* tgt_p = (const float*)d_in[1];
    const float* w_p   = (const float*)d_in[2];
    float* res = (float*)d_out;

    hipMemsetAsync(res, 0, sizeof(float), stream);
    ohkm_per_sample_kernel<<<BB, TPB, 0, stream>>>(out_p, tgt_p, w_p, res);
}

// Round 5
// 40.383 us; speedup vs baseline: 7.8526x; 1.2859x over previous
//
#include <hip/hip_runtime.h>
#include <math.h>

#define TOPK 8
#define KJ 17
#define BB 512
#define NROWS (BB * KJ)   // 8704
#define DF 3072           // floats per row; 768 float4; 3 float4/thread @ 256 thr

// Kernel 1: one block per (b,k) row. All 6 float4 loads issued up front
// (R1's runtime-count loop compiled to VGPR=8 -> no memory-level parallelism).
__global__ __launch_bounds__(256) void row_loss_kernel(
    const float* __restrict__ out,
    const float* __restrict__ tgt,
    const float* __restrict__ w,
    float* __restrict__ loss)
{
    const int row = blockIdx.x;
    const int tid = threadIdx.x;
    const size_t base = (size_t)row * DF;
    const float4* __restrict__ o4 = (const float4*)(out + base);
    const float4* __restrict__ t4 = (const float4*)(tgt + base);

    // batch all 6 loads before any math
    float4 a0 = o4[tid];
    float4 a1 = o4[tid + 256];
    float4 a2 = o4[tid + 512];
    float4 b0 = t4[tid];
    float4 b1 = t4[tid + 256];
    float4 b2 = t4[tid + 512];

    float dx = a0.x - b0.x, dy = a0.y - b0.y, dz = a0.z - b0.z, dw = a0.w - b0.w;
    float acc = dx * dx + dy * dy + dz * dz + dw * dw;
    dx = a1.x - b1.x; dy = a1.y - b1.y; dz = a1.z - b1.z; dw = a1.w - b1.w;
    acc += dx * dx + dy * dy + dz * dz + dw * dw;
    dx = a2.x - b2.x; dy = a2.y - b2.y; dz = a2.z - b2.z; dw = a2.w - b2.w;
    acc += dx * dx + dy * dy + dz * dz + dw * dw;

    #pragma unroll
    for (int off = 32; off > 0; off >>= 1)
        acc += __shfl_down(acc, off, 64);

    __shared__ float s[4];
    const int lane = tid & 63;
    const int wid = tid >> 6;
    if (lane == 0) s[wid] = acc;
    __syncthreads();
    if (tid == 0)
        loss[row] = (s[0] + s[1] + s[2] + s[3]) * w[row];
}

// Kernel 2: single block, one thread per batch element b.
__global__ __launch_bounds__(512) void topk_mean_kernel(
    const float* __restrict__ loss,
    float* __restrict__ outp)
{
    const int b = threadIdx.x;
    float per = 0.0f;

    {
        float v[KJ];
        #pragma unroll
        for (int k = 0; k < KJ; ++k)
            v[k] = loss[b * KJ + k];

        float sum8 = 0.0f;
        #pragma unroll
        for (int it = 0; it < TOPK; ++it) {
            float m = v[0];
            int mi = 0;
            #pragma unroll
            for (int k = 1; k < KJ; ++k)
                if (v[k] > m) { m = v[k]; mi = k; }
            sum8 += m;
            #pragma unroll
            for (int k = 0; k < KJ; ++k)
                v[k] = (k == mi) ? -INFINITY : v[k];
        }
        per = sum8 * (1.0f / (float)TOPK);
    }

    #pragma unroll
    for (int off = 32; off > 0; off >>= 1)
        per += __shfl_down(per, off, 64);

    __shared__ float s[8];
    const int lane = threadIdx.x & 63;
    const int wid = threadIdx.x >> 6;
    if (lane == 0) s[wid] = per;
    __syncthreads();
    if (threadIdx.x == 0) {
        float tot = 0.0f;
        #pragma unroll
        for (int i = 0; i < 8; ++i) tot += s[i];
        outp[0] = tot / (float)BB;
    }
}

extern "C" void kernel_launch(void* const* d_in, const int* in_sizes, int n_in,
                              void* d_out, int out_size, void* d_ws, size_t ws_size,
                              hipStream_t stream) {
    const float* out_p = (const float*)d_in[0];
    const float* tgt_p = (const float*)d_in[1];
    const float* w_p   = (const float*)d_in[2];
    float* res = (float*)d_out;

    float* loss_ws = (float*)d_ws;  // NROWS floats

    row_loss_kernel<<<NROWS, 256, 0, stream>>>(out_p, tgt_p, w_p, loss_ws);
    topk_mean_kernel<<<1, 512, 0, stream>>>(loss_ws, res);
}